// Round 8
// baseline (609.972 us; speedup 1.0000x reference)
//
#include <hip/hip_runtime.h>
#include <hip/hip_fp16.h>
#include <stdint.h>

#define B_ROWS 4096
#define N_PAT  8192
#define N_NEU  1024

typedef _Float16 f16x8 __attribute__((ext_vector_type(8)));
typedef _Float16 f16x4 __attribute__((ext_vector_type(4)));
typedef float    f32x4 __attribute__((ext_vector_type(4)));

__device__ __forceinline__ f32x4 mfma16(f16x8 a, f16x8 b, f32x4 c) {
  return __builtin_amdgcn_mfma_f32_16x16x32_f16(a, b, c, 0, 0, 0);
}

// ---------------- fp32 -> fp16 elementwise convert (vectorized) ----------------
__global__ __launch_bounds__(256) void convert_f32_f16(
    const float* __restrict__ in, _Float16* __restrict__ out, int n4) {
  int idx    = blockIdx.x * 256 + threadIdx.x;
  int stride = gridDim.x * 256;
  for (int i = idx; i < n4; i += stride) {
    float4 v = reinterpret_cast<const float4*>(in)[i];
    f16x4 h  = { (_Float16)v.x, (_Float16)v.y, (_Float16)v.z, (_Float16)v.w };
    reinterpret_cast<f16x4*>(out)[i] = h;
  }
}

// ---------------- fp32 [rows][cols] -> fp16 transpose [cols][rows] ----------------
__global__ __launch_bounds__(256) void transpose_f32_f16(
    const float* __restrict__ in, _Float16* __restrict__ out, int rows, int cols) {
  __shared__ float tile[32][33];
  int c0 = blockIdx.x * 32, r0 = blockIdx.y * 32;
  int tx = threadIdx.x, ty = threadIdx.y;  // 32 x 8
  #pragma unroll
  for (int i = 0; i < 32; i += 8)
    tile[ty + i][tx] = in[(size_t)(r0 + ty + i) * cols + c0 + tx];
  __syncthreads();
  #pragma unroll
  for (int i = 0; i < 32; i += 8)
    out[(size_t)(c0 + ty + i) * rows + r0 + tx] = (_Float16)tile[tx][ty + i];
}

// ---------------- async global->LDS, 16B per lane, wave-uniform LDS base ----------------
__device__ __forceinline__ void gload_lds16(const _Float16* g, _Float16* l) {
  __builtin_amdgcn_global_load_lds(
      (const __attribute__((address_space(1))) uint32_t*)g,
      (__attribute__((address_space(3))) uint32_t*)l, 16, 0, 0);
}

// ======== 256x256 tile, 8 waves, fragment-linear LDS, depth-2 counted-vmcnt ========
// C[z][M,N] = A[M,k0:k1] @ Bt[N,k0:k1]^T. BK=64, 2 LDS K-tile buffers (128 KiB).
//
// LDS layout (verified bit-exact r7, SQ_LDS_BANK_CONFLICT=0): each half-tile
// (128 rows x 64 k) stored in MFMA-FRAGMENT-LINEAR order,
//   elem (fr*2+ks)*512 + lane*8 + j == half[fr*16+(lane&15)][ks*32+(lane>>4)*8+j]
// staged by global_load_lds (linear dest) with per-thread pre-permuted global src.
// Every fragment ds_read_b128 is a lane-contiguous 1KB block -> conflict-free.
//
// Schedule (r5's depth-2 counted pipeline, the measured-best of rounds 2-7):
//   prologue: stage tile0->buf0, tile1->buf1; vmcnt(8) [tile0 landed]; barrier
//   tile tt:  read bf; 4x { read af quadrant; setprio(1) MFMA x16 setprio(0); barrier }
//             (4th barrier fences all waves' reads of buf)
//             stage tile tt+2 -> buf (just freed); s_waitcnt vmcnt(8)
//             [tt+1's 8 loads done, tt+2's 8 in flight - NEVER drains to 0]; barrier
// Ledger: stage(tt+2) writes buf(tt&1) read-fenced by phase-4 barrier; vmcnt(8)+
// barrier publishes tt+1's LDS to all waves before any read of buf^1.
template <typename OUT_T>
__global__ __launch_bounds__(512, 2) void gemm_8p(
    const _Float16* __restrict__ A, const _Float16* __restrict__ Bt,
    OUT_T* __restrict__ C, int M, int N, int K, int KS) {
  __shared__ _Float16 lds_[2][2][2][8192];  // [buf][mat][half][frag-linear]
  _Float16* const L = &lds_[0][0][0][0];
  const int t    = threadIdx.x;
  const int lane = t & 63;
  const int w    = t >> 6;       // wave 0..7
  const int wr   = w >> 2;       // M half -> wave tile 128x64
  const int wc   = w & 3;        // N quarter
  const int m0   = blockIdx.x * 256;
  const int n0   = blockIdx.y * 256;
  const int k0   = blockIdx.z * KS;

  // staging source (fragment-order permutation of the half-tile)
  const int r16  = t & 15;
  const int kgq  = (t >> 4) & 3;
  const int qq   = t >> 6;
  const int colo = (qq & 1) * 32 + kgq * 8;
  const int frow = (qq >> 1) * 16 + r16;
  const _Float16* sA = A  + (size_t)(m0 + frow) * K + colo + k0;
  const _Float16* sB = Bt + (size_t)(n0 + frow) * K + colo + k0;
  const size_t gj = (size_t)64 * K;    // g=1 jump (64 rows)
  const size_t hj = (size_t)128 * K;   // half jump

  const int bfr = (wc & 1) * 4;        // B frag-row base within its half
  const int NT  = KS >> 6;             // >= 16 for all uses here

  const int aOff = (wr << 13);                    // A: mat 0, half wr
  const int bOff = 16384 + ((wc >> 1) << 13);     // B: mat 1, half wc>>1
  const int rdo  = lane * 8;

  f32x4 acc[8][4] = {};

  auto stageA = [&](int bufn, int kt) {
    _Float16* d = L + (bufn << 15) + w * 512;
    gload_lds16(sA + kt,           d);
    gload_lds16(sA + gj + kt,      d + 4096);
    gload_lds16(sA + hj + kt,      d + 8192);
    gload_lds16(sA + hj + gj + kt, d + 12288);
  };
  auto stageB = [&](int bufn, int kt) {
    _Float16* d = L + (bufn << 15) + 16384 + w * 512;
    gload_lds16(sB + kt,           d);
    gload_lds16(sB + gj + kt,      d + 4096);
    gload_lds16(sB + hj + kt,      d + 8192);
    gload_lds16(sB + hj + gj + kt, d + 12288);
  };

#define LD_A(Ah, MI, KSL) \
  (*reinterpret_cast<const f16x8*>(&(Ah)[(((MI) * 2 + (KSL)) << 9) + rdo]))

#define DO_PHASE(MI0)                                                        \
  {                                                                          \
    f16x8 a0 = LD_A(Ah, MI0, 0), a1 = LD_A(Ah, MI0, 1);                      \
    f16x8 a2 = LD_A(Ah, (MI0) + 1, 0), a3 = LD_A(Ah, (MI0) + 1, 1);          \
    __builtin_amdgcn_s_setprio(1);                                           \
    _Pragma("unroll")                                                        \
    for (int ni = 0; ni < 4; ++ni) {                                         \
      acc[MI0][ni]       = mfma16(a0, bf[ni][0], acc[MI0][ni]);              \
      acc[MI0][ni]       = mfma16(a1, bf[ni][1], acc[MI0][ni]);              \
      acc[(MI0) + 1][ni] = mfma16(a2, bf[ni][0], acc[(MI0) + 1][ni]);        \
      acc[(MI0) + 1][ni] = mfma16(a3, bf[ni][1], acc[(MI0) + 1][ni]);        \
    }                                                                        \
    __builtin_amdgcn_s_setprio(0);                                           \
    __builtin_amdgcn_s_barrier();                                            \
  }

  // ---- prologue: tile 0 -> buf 0, tile 1 -> buf 1 (depth-2 pipeline fill)
  stageA(0, 0);
  stageB(0, 0);
  stageA(1, 64);
  stageB(1, 64);
  asm volatile("s_waitcnt vmcnt(8)" ::: "memory");  // tile 0 landed; tile 1 in flight
  __builtin_amdgcn_s_barrier();
  __builtin_amdgcn_sched_barrier(0);

  for (int tt = 0; tt < NT; ++tt) {
    const int buf = tt & 1;
    const _Float16* Ah = L + (buf << 15) + aOff;
    const _Float16* Bh = L + (buf << 15) + bOff;

    f16x8 bf[4][2];
    #pragma unroll
    for (int ni = 0; ni < 4; ++ni) {
      bf[ni][0] = *reinterpret_cast<const f16x8*>(&Bh[(((bfr + ni) * 2 + 0) << 9) + rdo]);
      bf[ni][1] = *reinterpret_cast<const f16x8*>(&Bh[(((bfr + ni) * 2 + 1) << 9) + rdo]);
    }
    DO_PHASE(0)
    DO_PHASE(2)
    DO_PHASE(4)
    DO_PHASE(6)   // 4th barrier: all waves done reading buf
    __builtin_amdgcn_sched_barrier(0);

    if (tt + 2 < NT) {
      const int kt2 = (tt + 2) << 6;
      stageA(buf, kt2);               // into the buffer this tile just freed
      stageB(buf, kt2);
      asm volatile("s_waitcnt vmcnt(8)" ::: "memory");  // tt+1 landed; tt+2 in flight
    } else {
      asm volatile("s_waitcnt vmcnt(0)" ::: "memory");  // pipeline epilogue
    }
    __builtin_amdgcn_s_barrier();     // publish tt+1's LDS to all waves
    __builtin_amdgcn_sched_barrier(0);
  }

  OUT_T* Cz = C + (size_t)blockIdx.z * M * N;
  const int crow = (lane >> 4) * 4;
  const int ccol = lane & 15;
  #pragma unroll
  for (int mi = 0; mi < 8; ++mi) {
    #pragma unroll
    for (int ni = 0; ni < 4; ++ni) {
      #pragma unroll
      for (int r = 0; r < 4; ++r) {
        int row = m0 + wr * 128 + mi * 16 + crow + r;
        int col = n0 + wc * 64 + ni * 16 + ccol;
        Cz[(size_t)row * N + col] = (OUT_T)acc[mi][ni][r];
      }
    }
  }
#undef LD_A
#undef DO_PHASE
}

// ---------------- sum SPLIT fp32 partials -> OUT_T ----------------
template <typename OUT_T, int SPLIT>
__global__ __launch_bounds__(256) void reduce_partials(
    const float* __restrict__ Cp, OUT_T* __restrict__ out, int n4, int stride4) {
  int idx    = blockIdx.x * 256 + threadIdx.x;
  int stride = gridDim.x * 256;
  for (int i = idx; i < n4; i += stride) {
    float4 a = reinterpret_cast<const float4*>(Cp)[i];
    #pragma unroll
    for (int s = 1; s < SPLIT; ++s) {
      float4 b = reinterpret_cast<const float4*>(Cp)[(size_t)s * stride4 + i];
      a.x += b.x; a.y += b.y; a.z += b.z; a.w += b.w;
    }
    if constexpr (sizeof(OUT_T) == 2) {
      f16x4 h = { (_Float16)a.x, (_Float16)a.y, (_Float16)a.z, (_Float16)a.w };
      reinterpret_cast<f16x4*>(out)[i] = h;
    } else {
      reinterpret_cast<float4*>(out)[i] = a;
    }
  }
}

// ---------------- in-place row softmax over N=8192 fp16 scores ----------------
__global__ __launch_bounds__(256) void softmax_rows(_Float16* __restrict__ S, int N) {
  const int t = threadIdx.x;
  f16x8* pv = reinterpret_cast<f16x8*>(S + (size_t)blockIdx.x * N);
  float v[32];
  float m = -3.0e38f;
  #pragma unroll
  for (int i = 0; i < 4; ++i) {
    f16x8 h = pv[i * 256 + t];
    #pragma unroll
    for (int e = 0; e < 8; ++e) {
      float f = (float)h[e];
      v[i * 8 + e] = f;
      m = fmaxf(m, f);
    }
  }
  #pragma unroll
  for (int o = 32; o; o >>= 1) m = fmaxf(m, __shfl_xor(m, o));
  __shared__ float redm[4];
  if ((t & 63) == 0) redm[t >> 6] = m;
  __syncthreads();
  m = fmaxf(fmaxf(redm[0], redm[1]), fmaxf(redm[2], redm[3]));

  float s = 0.f;
  #pragma unroll
  for (int i = 0; i < 32; ++i) { v[i] = __expf(v[i] - m); s += v[i]; }
  #pragma unroll
  for (int o = 32; o; o >>= 1) s += __shfl_xor(s, o);
  __shared__ float reds[4];
  if ((t & 63) == 0) reds[t >> 6] = s;
  __syncthreads();
  s = reds[0] + reds[1] + reds[2] + reds[3];
  const float inv = 1.0f / s;

  #pragma unroll
  for (int i = 0; i < 4; ++i) {
    f16x8 h;
    #pragma unroll
    for (int e = 0; e < 8; ++e) h[e] = (_Float16)(v[i * 8 + e] * inv);
    pv[i * 256 + t] = h;
  }
}

extern "C" void kernel_launch(void* const* d_in, const int* in_sizes, int n_in,
                              void* d_out, int out_size, void* d_ws, size_t ws_size,
                              hipStream_t stream) {
  const float* x        = (const float*)d_in[0];
  const float* patterns = (const float*)d_in[1];
  float* out            = (float*)d_out;
  char* ws = (char*)d_ws;

  _Float16* Xb   = (_Float16*)(ws);                          //   8 MB [4096][1024]
  _Float16* Pb   = (_Float16*)(ws + ((size_t)8  << 20));     //  16 MB [8192][1024]
  _Float16* PbT  = (_Float16*)(ws + ((size_t)24 << 20));     //  16 MB [1024][8192]
  _Float16* S    = (_Float16*)(ws + ((size_t)40 << 20));     //  64 MB [4096][8192]
  float*    part = (float*)   (ws + ((size_t)104 << 20));    //  split x 16 MB fp32 partials

  const size_t base = (size_t)104 << 20;
  const int split = (ws_size >= base + ((size_t)64 << 20)) ? 4
                  : (ws_size >= base + ((size_t)32 << 20)) ? 2 : 1;

  convert_f32_f16<<<dim3(1024), dim3(256), 0, stream>>>(x, Xb, (B_ROWS * N_NEU) / 4);
  convert_f32_f16<<<dim3(2048), dim3(256), 0, stream>>>(patterns, Pb, (N_PAT * N_NEU) / 4);
  transpose_f32_f16<<<dim3(N_NEU / 32, N_PAT / 32), dim3(32, 8), 0, stream>>>(patterns, PbT, N_PAT, N_NEU);

  const int n4 = (B_ROWS * N_NEU) / 4;
  const int stride4 = n4;

  for (int it = 0; it < 3; ++it) {
    // scores = Xb @ Pb^T  (TEMPERATURE == 1.0)  M=4096 N=8192 K=1024
    gemm_8p<_Float16><<<dim3(B_ROWS / 256, N_PAT / 256, 1), dim3(512), 0, stream>>>(
        Xb, Pb, S, B_ROWS, N_PAT, N_NEU, N_NEU);
    softmax_rows<<<dim3(B_ROWS), dim3(256), 0, stream>>>(S, N_PAT);

    // new_x = probs @ P == probs @ (PbT)^T   (M=4096, N=1024, K=8192)
    if (split > 1) {
      gemm_8p<float><<<dim3(B_ROWS / 256, N_NEU / 256, split), dim3(512), 0, stream>>>(
          S, PbT, part, B_ROWS, N_NEU, N_PAT, N_PAT / split);
      if (it < 2) {
        if (split == 4)
          reduce_partials<_Float16, 4><<<dim3(2048), dim3(256), 0, stream>>>(part, Xb, n4, stride4);
        else
          reduce_partials<_Float16, 2><<<dim3(2048), dim3(256), 0, stream>>>(part, Xb, n4, stride4);
      } else {
        if (split == 4)
          reduce_partials<float, 4><<<dim3(2048), dim3(256), 0, stream>>>(part, out, n4, stride4);
        else
          reduce_partials<float, 2><<<dim3(2048), dim3(256), 0, stream>>>(part, out, n4, stride4);
      }
    } else {
      gemm_8p<float><<<dim3(B_ROWS / 256, N_NEU / 256, 1), dim3(512), 0, stream>>>(
          S, PbT, part, B_ROWS, N_NEU, N_PAT, N_PAT);
      if (it < 2)
        reduce_partials<_Float16, 1><<<dim3(2048), dim3(256), 0, stream>>>(part, Xb, n4, stride4);
      else
        reduce_partials<float, 1><<<dim3(2048), dim3(256), 0, stream>>>(part, out, n4, stride4);
    }
  }
}

// Round 9
// 541.012 us; speedup vs baseline: 1.1275x; 1.1275x over previous
//
#include <hip/hip_runtime.h>
#include <hip/hip_fp16.h>
#include <stdint.h>

#define B_ROWS 4096
#define N_PAT  8192
#define N_NEU  1024

typedef _Float16 f16x8 __attribute__((ext_vector_type(8)));
typedef _Float16 f16x4 __attribute__((ext_vector_type(4)));
typedef float    f32x4 __attribute__((ext_vector_type(4)));

__device__ __forceinline__ f32x4 mfma16(f16x8 a, f16x8 b, f32x4 c) {
  return __builtin_amdgcn_mfma_f32_16x16x32_f16(a, b, c, 0, 0, 0);
}

// ---------------- fp32 -> fp16 elementwise convert (vectorized) ----------------
__global__ __launch_bounds__(256) void convert_f32_f16(
    const float* __restrict__ in, _Float16* __restrict__ out, int n4) {
  int idx    = blockIdx.x * 256 + threadIdx.x;
  int stride = gridDim.x * 256;
  for (int i = idx; i < n4; i += stride) {
    float4 v = reinterpret_cast<const float4*>(in)[i];
    f16x4 h  = { (_Float16)v.x, (_Float16)v.y, (_Float16)v.z, (_Float16)v.w };
    reinterpret_cast<f16x4*>(out)[i] = h;
  }
}

// ---------------- fp32 [rows][cols] -> fp16 transpose [cols][rows] ----------------
__global__ __launch_bounds__(256) void transpose_f32_f16(
    const float* __restrict__ in, _Float16* __restrict__ out, int rows, int cols) {
  __shared__ float tile[32][33];
  int c0 = blockIdx.x * 32, r0 = blockIdx.y * 32;
  int tx = threadIdx.x, ty = threadIdx.y;  // 32 x 8
  #pragma unroll
  for (int i = 0; i < 32; i += 8)
    tile[ty + i][tx] = in[(size_t)(r0 + ty + i) * cols + c0 + tx];
  __syncthreads();
  #pragma unroll
  for (int i = 0; i < 32; i += 8)
    out[(size_t)(c0 + ty + i) * rows + r0 + tx] = (_Float16)tile[tx][ty + i];
}

// ---------------- async global->LDS, 16B per lane, wave-uniform LDS base ----------------
__device__ __forceinline__ void gload_lds16(const _Float16* g, _Float16* l) {
  __builtin_amdgcn_global_load_lds(
      (const __attribute__((address_space(1))) uint32_t*)g,
      (__attribute__((address_space(3))) uint32_t*)l, 16, 0, 0);
}

// ======= 256x256 tile, 8 waves, XOR-swizzled row-major LDS, depth-2 counted vmcnt =======
// This is the round-5-measured-best structure (G1 ~79us), verbatim, plus OUT_T template
// and k0/KS split-K params. C[z][M,N] = A[M,k0:k1] @ Bt[N,k0:k1]^T.
//
// LDS: [slot][A|B][256 rows][64 k] row-major f16 (128B rows); granule (16B) g of row r
// stored at g^(r&7). Staging pre-swizzles the GLOBAL source (linear gload_lds dest,
// rule #21): lane reads granule (lane&7)^(row&7), so per 8-lane row-group the global
// segment is a full contiguous 128B line (best HBM/L2 coalescing - the r8 frag-linear
// layout fragmented this to 64B and lost 15us). Reads apply the same XOR: the 16
// row-lanes of a fragment spread over all 8 granule-columns -> 2 lanes/granule, free.
//
// Schedule (depth-2 counted pipeline):
//   prologue: stage tile0->slot0, tile1->slot1; vmcnt(8) [tile0 landed]; barrier
//   tile tt:  read bf (8 b128); 4 phases { read af quad; setprio(1) MFMA x16 setprio(0);
//             barrier (p<3) }; barrier; stage tile tt+2 -> slot tt&1 (just freed);
//             s_waitcnt vmcnt(8) [tt+1 landed, tt+2 in flight - never drains to 0]; barrier
template <typename OUT_T>
__global__ __launch_bounds__(512, 2) void gemm_x(
    const _Float16* __restrict__ A, const _Float16* __restrict__ Bt,
    OUT_T* __restrict__ C, int M, int N, int K, int KS) {
  __shared__ _Float16 lds[2][2][256 * 64];  // [slot][A/B][row*64]
  const int t    = threadIdx.x;
  const int lane = t & 63;
  const int w    = t >> 6;       // wave 0..7
  const int wr   = w >> 2;       // M half -> wave tile 128x64
  const int wc   = w & 3;        // N quarter
  const int m0   = blockIdx.x * 256;
  const int n0   = blockIdx.y * 256;
  const int k0   = blockIdx.z * KS;

  // staging: issue j covers rows j*64 + w*8 + (lane>>3); source granule pre-swizzled
  const int srow  = w * 8 + (lane >> 3);
  const int sgran = ((lane & 7) ^ ((lane >> 3) & 7)) * 8;
  const _Float16* sA = A  + (size_t)(m0 + srow) * K + sgran + k0;
  const _Float16* sB = Bt + (size_t)(n0 + srow) * K + sgran + k0;
  const size_t rj = (size_t)64 * K;   // row jump per issue
  const int ldst  = w * 512;          // wave-uniform LDS elem offset within issue chunk

  const int lrow = lane & 15;  // fragment row (A) / col (B)
  const int kg   = lane >> 4;  // k-group 0..3
  const int NT   = KS >> 6;

  f32x4 acc[8][4] = {};

  auto stage = [&](int slot, int kt) {
    #pragma unroll
    for (int j = 0; j < 4; ++j) {
      gload_lds16(sA + j * rj + kt, &lds[slot][0][j * 4096 + ldst]);
      gload_lds16(sB + j * rj + kt, &lds[slot][1][j * 4096 + ldst]);
    }
  };

  // ---- prologue: tile 0 -> slot 0, tile 1 -> slot 1 (depth-2 fill)
  stage(0, 0);
  stage(1, 64);
  asm volatile("s_waitcnt vmcnt(8)" ::: "memory");  // tile 0 landed; tile 1 in flight
  __builtin_amdgcn_s_barrier();
  __builtin_amdgcn_sched_barrier(0);

  for (int tt = 0; tt < NT; ++tt) {
    const int s = tt & 1;
    const _Float16* As = lds[s][0];
    const _Float16* Bs = lds[s][1];

    // B fragments for the whole K-tile (held across phases)
    f16x8 bf[4][2];
    #pragma unroll
    for (int ni = 0; ni < 4; ++ni) {
      const int br = wc * 64 + ni * 16 + lrow;
      #pragma unroll
      for (int ks = 0; ks < 2; ++ks)
        bf[ni][ks] = *reinterpret_cast<const f16x8*>(
            &Bs[br * 64 + (((ks * 4 + kg) ^ (br & 7)) * 8)]);
    }

    #pragma unroll
    for (int p = 0; p < 4; ++p) {
      f16x8 af[2][2];
      #pragma unroll
      for (int j = 0; j < 2; ++j) {
        const int ar = wr * 128 + (p * 2 + j) * 16 + lrow;
        #pragma unroll
        for (int ks = 0; ks < 2; ++ks)
          af[j][ks] = *reinterpret_cast<const f16x8*>(
              &As[ar * 64 + (((ks * 4 + kg) ^ (ar & 7)) * 8)]);
      }
      __builtin_amdgcn_s_setprio(1);
      #pragma unroll
      for (int j = 0; j < 2; ++j) {
        #pragma unroll
        for (int ni = 0; ni < 4; ++ni) {
          acc[p * 2 + j][ni] = mfma16(af[j][0], bf[ni][0], acc[p * 2 + j][ni]);
          acc[p * 2 + j][ni] = mfma16(af[j][1], bf[ni][1], acc[p * 2 + j][ni]);
        }
      }
      __builtin_amdgcn_s_setprio(0);
      if (p < 3) __builtin_amdgcn_s_barrier();
    }

    // all waves finished reading slot s (their MFMAs consumed every read)
    __builtin_amdgcn_s_barrier();
    __builtin_amdgcn_sched_barrier(0);
    if (tt + 2 < NT) {
      stage(s, (tt + 2) << 6);          // into the slot this tile just freed
      asm volatile("s_waitcnt vmcnt(8)" ::: "memory");  // tt+1 landed; tt+2 in flight
    } else {
      asm volatile("s_waitcnt vmcnt(0)" ::: "memory");  // pipeline epilogue
    }
    __builtin_amdgcn_s_barrier();       // publish tt+1's LDS to all waves
    __builtin_amdgcn_sched_barrier(0);
  }

  OUT_T* Cz = C + (size_t)blockIdx.z * M * N;
  const int crow = (lane >> 4) * 4;
  const int ccol = lane & 15;
  #pragma unroll
  for (int mi = 0; mi < 8; ++mi) {
    #pragma unroll
    for (int ni = 0; ni < 4; ++ni) {
      #pragma unroll
      for (int r = 0; r < 4; ++r) {
        int row = m0 + wr * 128 + mi * 16 + crow + r;
        int col = n0 + wc * 64 + ni * 16 + ccol;
        Cz[(size_t)row * N + col] = (OUT_T)acc[mi][ni][r];
      }
    }
  }
}

// ---------------- sum SPLIT fp32 partials -> OUT_T ----------------
template <typename OUT_T, int SPLIT>
__global__ __launch_bounds__(256) void reduce_partials(
    const float* __restrict__ Cp, OUT_T* __restrict__ out, int n4, int stride4) {
  int idx    = blockIdx.x * 256 + threadIdx.x;
  int stride = gridDim.x * 256;
  for (int i = idx; i < n4; i += stride) {
    float4 a = reinterpret_cast<const float4*>(Cp)[i];
    #pragma unroll
    for (int s = 1; s < SPLIT; ++s) {
      float4 b = reinterpret_cast<const float4*>(Cp)[(size_t)s * stride4 + i];
      a.x += b.x; a.y += b.y; a.z += b.z; a.w += b.w;
    }
    if constexpr (sizeof(OUT_T) == 2) {
      f16x4 h = { (_Float16)a.x, (_Float16)a.y, (_Float16)a.z, (_Float16)a.w };
      reinterpret_cast<f16x4*>(out)[i] = h;
    } else {
      reinterpret_cast<float4*>(out)[i] = a;
    }
  }
}

// ---------------- in-place row softmax over N=8192 fp16 scores ----------------
__global__ __launch_bounds__(256) void softmax_rows(_Float16* __restrict__ S, int N) {
  const int t = threadIdx.x;
  f16x8* pv = reinterpret_cast<f16x8*>(S + (size_t)blockIdx.x * N);
  float v[32];
  float m = -3.0e38f;
  #pragma unroll
  for (int i = 0; i < 4; ++i) {
    f16x8 h = pv[i * 256 + t];
    #pragma unroll
    for (int e = 0; e < 8; ++e) {
      float f = (float)h[e];
      v[i * 8 + e] = f;
      m = fmaxf(m, f);
    }
  }
  #pragma unroll
  for (int o = 32; o; o >>= 1) m = fmaxf(m, __shfl_xor(m, o));
  __shared__ float redm[4];
  if ((t & 63) == 0) redm[t >> 6] = m;
  __syncthreads();
  m = fmaxf(fmaxf(redm[0], redm[1]), fmaxf(redm[2], redm[3]));

  float s = 0.f;
  #pragma unroll
  for (int i = 0; i < 32; ++i) { v[i] = __expf(v[i] - m); s += v[i]; }
  #pragma unroll
  for (int o = 32; o; o >>= 1) s += __shfl_xor(s, o);
  __shared__ float reds[4];
  if ((t & 63) == 0) reds[t >> 6] = s;
  __syncthreads();
  s = reds[0] + reds[1] + reds[2] + reds[3];
  const float inv = 1.0f / s;

  #pragma unroll
  for (int i = 0; i < 4; ++i) {
    f16x8 h;
    #pragma unroll
    for (int e = 0; e < 8; ++e) h[e] = (_Float16)(v[i * 8 + e] * inv);
    pv[i * 256 + t] = h;
  }
}

extern "C" void kernel_launch(void* const* d_in, const int* in_sizes, int n_in,
                              void* d_out, int out_size, void* d_ws, size_t ws_size,
                              hipStream_t stream) {
  const float* x        = (const float*)d_in[0];
  const float* patterns = (const float*)d_in[1];
  float* out            = (float*)d_out;
  char* ws = (char*)d_ws;

  _Float16* Xb   = (_Float16*)(ws);                          //   8 MB [4096][1024]
  _Float16* Pb   = (_Float16*)(ws + ((size_t)8  << 20));     //  16 MB [8192][1024]
  _Float16* PbT  = (_Float16*)(ws + ((size_t)24 << 20));     //  16 MB [1024][8192]
  _Float16* S    = (_Float16*)(ws + ((size_t)40 << 20));     //  64 MB [4096][8192]
  float*    part = (float*)   (ws + ((size_t)104 << 20));    //  split x 16 MB fp32 partials

  const size_t base = (size_t)104 << 20;
  const int split = (ws_size >= base + ((size_t)64 << 20)) ? 4
                  : (ws_size >= base + ((size_t)32 << 20)) ? 2 : 1;

  convert_f32_f16<<<dim3(1024), dim3(256), 0, stream>>>(x, Xb, (B_ROWS * N_NEU) / 4);
  convert_f32_f16<<<dim3(2048), dim3(256), 0, stream>>>(patterns, Pb, (N_PAT * N_NEU) / 4);
  transpose_f32_f16<<<dim3(N_NEU / 32, N_PAT / 32), dim3(32, 8), 0, stream>>>(patterns, PbT, N_PAT, N_NEU);

  const int n4 = (B_ROWS * N_NEU) / 4;
  const int stride4 = n4;

  for (int it = 0; it < 3; ++it) {
    // scores = Xb @ Pb^T  (TEMPERATURE == 1.0)  M=4096 N=8192 K=1024
    gemm_x<_Float16><<<dim3(B_ROWS / 256, N_PAT / 256, 1), dim3(512), 0, stream>>>(
        Xb, Pb, S, B_ROWS, N_PAT, N_NEU, N_NEU);
    softmax_rows<<<dim3(B_ROWS), dim3(256), 0, stream>>>(S, N_PAT);

    // new_x = probs @ P == probs @ (PbT)^T   (M=4096, N=1024, K=8192)
    if (split > 1) {
      gemm_x<float><<<dim3(B_ROWS / 256, N_NEU / 256, split), dim3(512), 0, stream>>>(
          S, PbT, part, B_ROWS, N_NEU, N_PAT, N_PAT / split);
      if (it < 2) {
        if (split == 4)
          reduce_partials<_Float16, 4><<<dim3(2048), dim3(256), 0, stream>>>(part, Xb, n4, stride4);
        else
          reduce_partials<_Float16, 2><<<dim3(2048), dim3(256), 0, stream>>>(part, Xb, n4, stride4);
      } else {
        if (split == 4)
          reduce_partials<float, 4><<<dim3(2048), dim3(256), 0, stream>>>(part, out, n4, stride4);
        else
          reduce_partials<float, 2><<<dim3(2048), dim3(256), 0, stream>>>(part, out, n4, stride4);
      }
    } else {
      gemm_x<float><<<dim3(B_ROWS / 256, N_NEU / 256, 1), dim3(512), 0, stream>>>(
          S, PbT, part, B_ROWS, N_NEU, N_PAT, N_PAT);
      if (it < 2)
        reduce_partials<_Float16, 1><<<dim3(2048), dim3(256), 0, stream>>>(part, Xb, n4, stride4);
      else
        reduce_partials<float, 1><<<dim3(2048), dim3(256), 0, stream>>>(part, out, n4, stride4);
    }
  }
}

// Round 10
// 535.088 us; speedup vs baseline: 1.1399x; 1.0111x over previous
//
#include <hip/hip_runtime.h>
#include <hip/hip_fp16.h>
#include <stdint.h>

#define B_ROWS 4096
#define N_PAT  8192
#define N_NEU  1024

typedef _Float16 f16x8 __attribute__((ext_vector_type(8)));
typedef _Float16 f16x4 __attribute__((ext_vector_type(4)));
typedef float    f32x4 __attribute__((ext_vector_type(4)));

__device__ __forceinline__ f32x4 mfma16(f16x8 a, f16x8 b, f32x4 c) {
  return __builtin_amdgcn_mfma_f32_16x16x32_f16(a, b, c, 0, 0, 0);
}

// ---------------- fp32 -> fp16 elementwise convert (vectorized) ----------------
__global__ __launch_bounds__(256) void convert_f32_f16(
    const float* __restrict__ in, _Float16* __restrict__ out, int n4) {
  int idx    = blockIdx.x * 256 + threadIdx.x;
  int stride = gridDim.x * 256;
  for (int i = idx; i < n4; i += stride) {
    float4 v = reinterpret_cast<const float4*>(in)[i];
    f16x4 h  = { (_Float16)v.x, (_Float16)v.y, (_Float16)v.z, (_Float16)v.w };
    reinterpret_cast<f16x4*>(out)[i] = h;
  }
}

// ---------------- fp32 [rows][cols] -> fp16 transpose [cols][rows] ----------------
__global__ __launch_bounds__(256) void transpose_f32_f16(
    const float* __restrict__ in, _Float16* __restrict__ out, int rows, int cols) {
  __shared__ float tile[32][33];
  int c0 = blockIdx.x * 32, r0 = blockIdx.y * 32;
  int tx = threadIdx.x, ty = threadIdx.y;  // 32 x 8
  #pragma unroll
  for (int i = 0; i < 32; i += 8)
    tile[ty + i][tx] = in[(size_t)(r0 + ty + i) * cols + c0 + tx];
  __syncthreads();
  #pragma unroll
  for (int i = 0; i < 32; i += 8)
    out[(size_t)(c0 + ty + i) * rows + r0 + tx] = (_Float16)tile[tx][ty + i];
}

// ---------------- async global->LDS, 16B per lane, wave-uniform LDS base ----------------
__device__ __forceinline__ void gload_lds16(const _Float16* g, _Float16* l) {
  __builtin_amdgcn_global_load_lds(
      (const __attribute__((address_space(1))) uint32_t*)g,
      (__attribute__((address_space(3))) uint32_t*)l, 16, 0, 0);
}

// ======= 256x256 tile, 8 waves, XOR-swizzled row-major LDS, depth-2 counted vmcnt =======
// r9 structure (measured best: 541us total) with the 3 INTRA-TILE barriers removed.
// Rationale (r9 cycle arithmetic): per K-tile per CU, MFMA ~2483 cyc and LDS-read
// ~2260 cyc are co-critical; intra-tile barriers locked all 8 waves into the same
// micro-state (everyone reads, then everyone MFMAs), serializing the two pipes.
// Removing them lets waves drift within the tile window so one wave's ds_reads
// overlap another's MFMAs. Correctness needs only the tile-boundary fences:
//   read-fence barrier (all waves' reads of slot s done) -> stage(tt+2) -> vmcnt(8)
//   [tt+1 landed, tt+2 in flight, never drains to 0] -> publish barrier.
template <typename OUT_T>
__global__ __launch_bounds__(512, 2) void gemm_x(
    const _Float16* __restrict__ A, const _Float16* __restrict__ Bt,
    OUT_T* __restrict__ C, int M, int N, int K, int KS) {
  __shared__ _Float16 lds[2][2][256 * 64];  // [slot][A/B][row*64]
  const int t    = threadIdx.x;
  const int lane = t & 63;
  const int w    = t >> 6;       // wave 0..7
  const int wr   = w >> 2;       // M half -> wave tile 128x64
  const int wc   = w & 3;        // N quarter
  const int m0   = blockIdx.x * 256;
  const int n0   = blockIdx.y * 256;
  const int k0   = blockIdx.z * KS;

  // staging: issue j covers rows j*64 + w*8 + (lane>>3); source granule pre-swizzled
  // (lane&7)^(row&7) so the LDS granule column is XOR'd while the global segment per
  // 8-lane row-group stays a contiguous 128B line (r8 lesson: keep staging coalesced).
  const int srow  = w * 8 + (lane >> 3);
  const int sgran = ((lane & 7) ^ ((lane >> 3) & 7)) * 8;
  const _Float16* sA = A  + (size_t)(m0 + srow) * K + sgran + k0;
  const _Float16* sB = Bt + (size_t)(n0 + srow) * K + sgran + k0;
  const size_t rj = (size_t)64 * K;   // row jump per issue
  const int ldst  = w * 512;          // wave-uniform LDS elem offset within issue chunk

  const int lrow = lane & 15;  // fragment row (A) / col (B)
  const int kg   = lane >> 4;  // k-group 0..3
  const int NT   = KS >> 6;

  f32x4 acc[8][4] = {};

  auto stage = [&](int slot, int kt) {
    #pragma unroll
    for (int j = 0; j < 4; ++j) {
      gload_lds16(sA + j * rj + kt, &lds[slot][0][j * 4096 + ldst]);
      gload_lds16(sB + j * rj + kt, &lds[slot][1][j * 4096 + ldst]);
    }
  };

  // ---- prologue: tile 0 -> slot 0, tile 1 -> slot 1 (depth-2 fill)
  stage(0, 0);
  stage(1, 64);
  asm volatile("s_waitcnt vmcnt(8)" ::: "memory");  // tile 0 landed; tile 1 in flight
  __builtin_amdgcn_s_barrier();
  __builtin_amdgcn_sched_barrier(0);

  for (int tt = 0; tt < NT; ++tt) {
    const int s = tt & 1;
    const _Float16* As = lds[s][0];
    const _Float16* Bs = lds[s][1];

    // B fragments for the whole K-tile (held across phases)
    f16x8 bf[4][2];
    #pragma unroll
    for (int ni = 0; ni < 4; ++ni) {
      const int br = wc * 64 + ni * 16 + lrow;
      #pragma unroll
      for (int ks = 0; ks < 2; ++ks)
        bf[ni][ks] = *reinterpret_cast<const f16x8*>(
            &Bs[br * 64 + (((ks * 4 + kg) ^ (br & 7)) * 8)]);
    }

    #pragma unroll
    for (int p = 0; p < 4; ++p) {
      f16x8 af[2][2];
      #pragma unroll
      for (int j = 0; j < 2; ++j) {
        const int ar = wr * 128 + (p * 2 + j) * 16 + lrow;
        #pragma unroll
        for (int ks = 0; ks < 2; ++ks)
          af[j][ks] = *reinterpret_cast<const f16x8*>(
              &As[ar * 64 + (((ks * 4 + kg) ^ (ar & 7)) * 8)]);
      }
      __builtin_amdgcn_s_setprio(1);
      #pragma unroll
      for (int j = 0; j < 2; ++j) {
        #pragma unroll
        for (int ni = 0; ni < 4; ++ni) {
          acc[p * 2 + j][ni] = mfma16(af[j][0], bf[ni][0], acc[p * 2 + j][ni]);
          acc[p * 2 + j][ni] = mfma16(af[j][1], bf[ni][1], acc[p * 2 + j][ni]);
        }
      }
      __builtin_amdgcn_s_setprio(0);
      // no intra-tile barrier: waves drift -> LDS-read pipe overlaps MFMA pipe
    }

    // tile-boundary fence: all waves finished reading slot s
    __builtin_amdgcn_s_barrier();
    __builtin_amdgcn_sched_barrier(0);
    if (tt + 2 < NT) {
      stage(s, (tt + 2) << 6);          // into the slot this tile just freed
      asm volatile("s_waitcnt vmcnt(8)" ::: "memory");  // tt+1 landed; tt+2 in flight
    } else {
      asm volatile("s_waitcnt vmcnt(0)" ::: "memory");  // pipeline epilogue
    }
    __builtin_amdgcn_s_barrier();       // publish tt+1's LDS to all waves
    __builtin_amdgcn_sched_barrier(0);
  }

  OUT_T* Cz = C + (size_t)blockIdx.z * M * N;
  const int crow = (lane >> 4) * 4;
  const int ccol = lane & 15;
  #pragma unroll
  for (int mi = 0; mi < 8; ++mi) {
    #pragma unroll
    for (int ni = 0; ni < 4; ++ni) {
      #pragma unroll
      for (int r = 0; r < 4; ++r) {
        int row = m0 + wr * 128 + mi * 16 + crow + r;
        int col = n0 + wc * 64 + ni * 16 + ccol;
        Cz[(size_t)row * N + col] = (OUT_T)acc[mi][ni][r];
      }
    }
  }
}

// ---------------- sum SPLIT fp32 partials -> OUT_T ----------------
template <typename OUT_T, int SPLIT>
__global__ __launch_bounds__(256) void reduce_partials(
    const float* __restrict__ Cp, OUT_T* __restrict__ out, int n4, int stride4) {
  int idx    = blockIdx.x * 256 + threadIdx.x;
  int stride = gridDim.x * 256;
  for (int i = idx; i < n4; i += stride) {
    float4 a = reinterpret_cast<const float4*>(Cp)[i];
    #pragma unroll
    for (int s = 1; s < SPLIT; ++s) {
      float4 b = reinterpret_cast<const float4*>(Cp)[(size_t)s * stride4 + i];
      a.x += b.x; a.y += b.y; a.z += b.z; a.w += b.w;
    }
    if constexpr (sizeof(OUT_T) == 2) {
      f16x4 h = { (_Float16)a.x, (_Float16)a.y, (_Float16)a.z, (_Float16)a.w };
      reinterpret_cast<f16x4*>(out)[i] = h;
    } else {
      reinterpret_cast<float4*>(out)[i] = a;
    }
  }
}

// ---------------- in-place row softmax over N=8192 fp16 scores ----------------
__global__ __launch_bounds__(256) void softmax_rows(_Float16* __restrict__ S, int N) {
  const int t = threadIdx.x;
  f16x8* pv = reinterpret_cast<f16x8*>(S + (size_t)blockIdx.x * N);
  float v[32];
  float m = -3.0e38f;
  #pragma unroll
  for (int i = 0; i < 4; ++i) {
    f16x8 h = pv[i * 256 + t];
    #pragma unroll
    for (int e = 0; e < 8; ++e) {
      float f = (float)h[e];
      v[i * 8 + e] = f;
      m = fmaxf(m, f);
    }
  }
  #pragma unroll
  for (int o = 32; o; o >>= 1) m = fmaxf(m, __shfl_xor(m, o));
  __shared__ float redm[4];
  if ((t & 63) == 0) redm[t >> 6] = m;
  __syncthreads();
  m = fmaxf(fmaxf(redm[0], redm[1]), fmaxf(redm[2], redm[3]));

  float s = 0.f;
  #pragma unroll
  for (int i = 0; i < 32; ++i) { v[i] = __expf(v[i] - m); s += v[i]; }
  #pragma unroll
  for (int o = 32; o; o >>= 1) s += __shfl_xor(s, o);
  __shared__ float reds[4];
  if ((t & 63) == 0) reds[t >> 6] = s;
  __syncthreads();
  s = reds[0] + reds[1] + reds[2] + reds[3];
  const float inv = 1.0f / s;

  #pragma unroll
  for (int i = 0; i < 4; ++i) {
    f16x8 h;
    #pragma unroll
    for (int e = 0; e < 8; ++e) h[e] = (_Float16)(v[i * 8 + e] * inv);
    pv[i * 256 + t] = h;
  }
}

extern "C" void kernel_launch(void* const* d_in, const int* in_sizes, int n_in,
                              void* d_out, int out_size, void* d_ws, size_t ws_size,
                              hipStream_t stream) {
  const float* x        = (const float*)d_in[0];
  const float* patterns = (const float*)d_in[1];
  float* out            = (float*)d_out;
  char* ws = (char*)d_ws;

  _Float16* Xb   = (_Float16*)(ws);                          //   8 MB [4096][1024]
  _Float16* Pb   = (_Float16*)(ws + ((size_t)8  << 20));     //  16 MB [8192][1024]
  _Float16* PbT  = (_Float16*)(ws + ((size_t)24 << 20));     //  16 MB [1024][8192]
  _Float16* S    = (_Float16*)(ws + ((size_t)40 << 20));     //  64 MB [4096][8192]
  float*    part = (float*)   (ws + ((size_t)104 << 20));    //  split x 16 MB fp32 partials

  const size_t base = (size_t)104 << 20;
  const int split = (ws_size >= base + ((size_t)64 << 20)) ? 4
                  : (ws_size >= base + ((size_t)32 << 20)) ? 2 : 1;

  convert_f32_f16<<<dim3(1024), dim3(256), 0, stream>>>(x, Xb, (B_ROWS * N_NEU) / 4);
  convert_f32_f16<<<dim3(2048), dim3(256), 0, stream>>>(patterns, Pb, (N_PAT * N_NEU) / 4);
  transpose_f32_f16<<<dim3(N_NEU / 32, N_PAT / 32), dim3(32, 8), 0, stream>>>(patterns, PbT, N_PAT, N_NEU);

  const int n4 = (B_ROWS * N_NEU) / 4;
  const int stride4 = n4;

  for (int it = 0; it < 3; ++it) {
    // scores = Xb @ Pb^T  (TEMPERATURE == 1.0)  M=4096 N=8192 K=1024
    gemm_x<_Float16><<<dim3(B_ROWS / 256, N_PAT / 256, 1), dim3(512), 0, stream>>>(
        Xb, Pb, S, B_ROWS, N_PAT, N_NEU, N_NEU);
    softmax_rows<<<dim3(B_ROWS), dim3(256), 0, stream>>>(S, N_PAT);

    // new_x = probs @ P == probs @ (PbT)^T   (M=4096, N=1024, K=8192)
    if (split > 1) {
      gemm_x<float><<<dim3(B_ROWS / 256, N_NEU / 256, split), dim3(512), 0, stream>>>(
          S, PbT, part, B_ROWS, N_NEU, N_PAT, N_PAT / split);
      if (it < 2) {
        if (split == 4)
          reduce_partials<_Float16, 4><<<dim3(2048), dim3(256), 0, stream>>>(part, Xb, n4, stride4);
        else
          reduce_partials<_Float16, 2><<<dim3(2048), dim3(256), 0, stream>>>(part, Xb, n4, stride4);
      } else {
        if (split == 4)
          reduce_partials<float, 4><<<dim3(2048), dim3(256), 0, stream>>>(part, out, n4, stride4);
        else
          reduce_partials<float, 2><<<dim3(2048), dim3(256), 0, stream>>>(part, out, n4, stride4);
      }
    } else {
      gemm_x<float><<<dim3(B_ROWS / 256, N_NEU / 256, 1), dim3(512), 0, stream>>>(
          S, PbT, part, B_ROWS, N_NEU, N_PAT, N_PAT);
      if (it < 2)
        reduce_partials<_Float16, 1><<<dim3(2048), dim3(256), 0, stream>>>(part, Xb, n4, stride4);
      else
        reduce_partials<float, 1><<<dim3(2048), dim3(256), 0, stream>>>(part, out, n4, stride4);
    }
  }
}